// Round 10
// baseline (413.197 us; speedup 1.0000x reference)
//
#include <hip/hip_runtime.h>
#include <hip/hip_bf16.h>
#include <stdint.h>

typedef __bf16 bf16_t;
typedef __bf16 bf16x8 __attribute__((ext_vector_type(8)));
typedef __bf16 bf16x4 __attribute__((ext_vector_type(4)));
typedef float f32x4 __attribute__((ext_vector_type(4)));

#define T_TOK 4096
#define DIM   1024
#define HID   2048
#define NE    8
#define MAXT  72   // max 128-row m-tiles: 8192/128 + 8

// async global->LDS, 16B per lane, LDS dest = wave-uniform base + lane*16
__device__ __forceinline__ void gload_lds16(const void* g, void* l) {
  __builtin_amdgcn_global_load_lds(
      (const __attribute__((address_space(1))) unsigned int*)g,
      (__attribute__((address_space(3))) unsigned int*)l, 16, 0, 0);
}

// ---------------- weight transpose+convert: in [K][N] f32 -> out [N][K] bf16 ----------------
__global__ __launch_bounds__(256) void k_wt(const float* __restrict__ in,
                                            bf16_t* __restrict__ out,
                                            int K, int N) {
  __shared__ float tile[64][65];
  const size_t eoff = (size_t)blockIdx.z * K * N;
  const int k0 = blockIdx.y * 64, n0 = blockIdx.x * 64;
  const int tid = threadIdx.x;
#pragma unroll
  for (int it = 0; it < 4; ++it) {
    int k = (tid >> 4) + it * 16;
    int n = (tid & 15) * 4;
    float4 v = *(const float4*)(in + eoff + (size_t)(k0 + k) * N + n0 + n);
    tile[k][n] = v.x; tile[k][n + 1] = v.y; tile[k][n + 2] = v.z; tile[k][n + 3] = v.w;
  }
  __syncthreads();
#pragma unroll
  for (int it = 0; it < 2; ++it) {
    int n = (tid >> 3) + it * 32;
    int kc = (tid & 7) * 8;
    bf16x8 o;
#pragma unroll
    for (int j = 0; j < 8; ++j) o[j] = (bf16_t)tile[kc + j][n];
    *(bf16x8*)(out + eoff + (size_t)(n0 + n) * K + k0 + kc) = o;
  }
}

// ---------------- router (+ fused x->bf16): logits, sigmoid, top-2, aux ----------------
__global__ __launch_bounds__(256) void k_router(const float* __restrict__ x,
    const float* __restrict__ rw, const float* __restrict__ rb,
    int* __restrict__ counts, int* __restrict__ top_i, float* __restrict__ top_w,
    float* __restrict__ aux, bf16_t* __restrict__ xb) {
  int t = blockIdx.x * 4 + (threadIdx.x >> 6);
  int lane = threadIdx.x & 63;
  const float* xt = x + (size_t)t * DIM;
  float acc[8] = {0.f,0.f,0.f,0.f,0.f,0.f,0.f,0.f};
#pragma unroll
  for (int it = 0; it < 4; ++it) {
    int i = (it * 64 + lane) * 4;
    float4 xv = *(const float4*)(xt + i);
    bf16x4 o;
    o[0] = (bf16_t)xv.x; o[1] = (bf16_t)xv.y; o[2] = (bf16_t)xv.z; o[3] = (bf16_t)xv.w;
    *(bf16x4*)(xb + (size_t)t * DIM + i) = o;
#pragma unroll
    for (int c = 0; c < 4; ++c) {
      float v = (c == 0) ? xv.x : (c == 1) ? xv.y : (c == 2) ? xv.z : xv.w;
      float4 r0 = *(const float4*)(rw + (size_t)(i + c) * 8);
      float4 r1 = *(const float4*)(rw + (size_t)(i + c) * 8 + 4);
      acc[0] += v * r0.x; acc[1] += v * r0.y; acc[2] += v * r0.z; acc[3] += v * r0.w;
      acc[4] += v * r1.x; acc[5] += v * r1.y; acc[6] += v * r1.z; acc[7] += v * r1.w;
    }
  }
#pragma unroll
  for (int m = 32; m >= 1; m >>= 1) {
#pragma unroll
    for (int e = 0; e < 8; ++e) acc[e] += __shfl_xor(acc[e], m, 64);
  }
  if (lane == 0) {
    float s[8]; float sumsq = 0.f;
#pragma unroll
    for (int e = 0; e < 8; ++e) {
      float lg = acc[e] + rb[e];
      sumsq += lg * lg;
      s[e] = 1.f / (1.f + __expf(-lg));
    }
    int i1 = 0;
#pragma unroll
    for (int e = 1; e < 8; ++e) if (s[e] > s[i1]) i1 = e;
    int i2 = (i1 == 0) ? 1 : 0;
#pragma unroll
    for (int e = 0; e < 8; ++e) if (e != i1 && s[e] > s[i2]) i2 = e;
    float v1 = s[i1], v2 = s[i2];
    float den = v1 + v2 + 1e-6f;
    top_i[2 * t]     = i1; top_i[2 * t + 1] = i2;
    top_w[2 * t]     = v1 / den;
    top_w[2 * t + 1] = v2 / den;
    atomicAdd(&counts[i1], 1);
    atomicAdd(&counts[i2], 1);
    atomicAdd(aux, 0.01f * sumsq * (1.f / 32768.f));
  }
}

// ---------------- plan: base offsets + m-tile table ----------------
__global__ void k_plan(const int* __restrict__ counts, int* __restrict__ base,
                       int* __restrict__ tile_e, int* __restrict__ tile_m0) {
  if (threadIdx.x == 0) {
    int s = 0, nt = 0;
    for (int e = 0; e < NE; ++e) {
      base[e] = s;
      int c = counts[e];
      for (int m0 = 0; m0 < c; m0 += 128) { tile_e[nt] = e; tile_m0[nt] = m0; ++nt; }
      s += c;
    }
    for (; nt < MAXT; ++nt) tile_e[nt] = -1;
  }
}

// ---------------- gather tokens into per-expert slot lists ----------------
__global__ __launch_bounds__(256) void k_gather(const int* __restrict__ top_i,
    const float* __restrict__ top_w, const int* __restrict__ base,
    int* __restrict__ fill, int* __restrict__ slot_token, float* __restrict__ slot_wt,
    int* __restrict__ slot_of) {
  int t = blockIdx.x * 256 + threadIdx.x;
  if (t >= T_TOK) return;
#pragma unroll
  for (int j = 0; j < 2; ++j) {
    int e = top_i[2 * t + j];
    int p = atomicAdd(&fill[e], 1);
    int g = base[e] + p;
    slot_token[g] = t;
    slot_wt[g]    = top_w[2 * t + j];
    slot_of[2 * t + j] = g;
  }
}

// ---------------- GEMM1 + SwiGLU: BK=32, 32 KB dbuf LDS -> 4 blocks/CU ----------------
// tile 128m x 64n (two panels). 4 waves 2x2. grid = (HID/64 = 32, MAXT).
// counted-vmcnt pipeline: stage=4 loads/thread, steady-state vmcnt(4).
// additive chunk rotation: phys = (logical + (row>>1)) & 3  -> 2-way banks (free).
__global__ __launch_bounds__(256) void k_gemm1(
    const bf16_t* __restrict__ xb, const bf16_t* __restrict__ w12t,
    const int* __restrict__ counts, const int* __restrict__ base,
    const int* __restrict__ tile_e, const int* __restrict__ tile_m0,
    const int* __restrict__ slot_token, bf16_t* __restrict__ h) {
  const int e = tile_e[blockIdx.y];
  if (e < 0) return;
  const int m0  = tile_m0[blockIdx.y];
  const int cnt = counts[e];
  const int bas = base[e];
  const int n0  = blockIdx.x * 64;          // hid col base, [0,2048)
  const bf16_t* W1 = w12t + (size_t)e * (4096u * 1024u) + (size_t)n0 * 1024u;
  const bf16_t* W2 = W1 + (size_t)2048 * 1024;

  __shared__ bf16_t sA[2][128 * 32];   // 8 KB x2
  __shared__ bf16_t sB1[2][64 * 32];   // 4 KB x2
  __shared__ bf16_t sB2[2][64 * 32];   // 4 KB x2   -> 32 KB total

  const int tid = threadIdx.x, lane = tid & 63, wid = tid >> 6;
  const int wr = wid >> 1, wc = wid & 1;
  // source chunk (elements offset = cl*8): inverse of phys=(log+(row>>1))&3 at phys=lane&3
  const int cl = ((lane & 3) - ((lane >> 3) & 3)) & 3;
  // read chunk: phys = (g + (row>>1)) & 3, g = lane>>4, row = ...+(lane&15)
  const int s4 = ((lane >> 4) + ((lane & 15) >> 1)) & 3;

  int tokA[2];
#pragma unroll
  for (int i = 0; i < 2; ++i) {
    int row = m0 + i * 64 + wid * 16 + (lane >> 2);
    tokA[i] = slot_token[bas + (row < cnt ? row : cnt - 1)];
  }
  const int nrow = wid * 16 + (lane >> 2);

  auto stage = [&](int p, int k0) {
#pragma unroll
    for (int i = 0; i < 2; ++i)
      gload_lds16(xb + (size_t)tokA[i] * DIM + k0 + cl * 8,
                  &sA[p][(i * 64 + wid * 16) * 32]);
    gload_lds16(W1 + (size_t)nrow * 1024 + k0 + cl * 8, &sB1[p][(wid * 16) * 32]);
    gload_lds16(W2 + (size_t)nrow * 1024 + k0 + cl * 8, &sB2[p][(wid * 16) * 32]);
  };

  f32x4 acc1[4][2] = {};
  f32x4 acc2[4][2] = {};

  stage(0, 0);
  stage(1, 32);

  const int NT = DIM / 32;  // 32
  for (int t = 0; t < NT; ++t) {
    const int p = t & 1;
    if (t + 2 < NT) asm volatile("s_waitcnt vmcnt(4)" ::: "memory");
    else            asm volatile("s_waitcnt vmcnt(0)" ::: "memory");
    __builtin_amdgcn_s_barrier();
    asm volatile("" ::: "memory");
    __builtin_amdgcn_s_setprio(1);
    {
      bf16x8 a[4], b1[2], b2[2];
#pragma unroll
      for (int mf = 0; mf < 4; ++mf) {
        int r = wr * 64 + mf * 16 + (lane & 15);
        a[mf] = *(const bf16x8*)(&sA[p][r * 32 + s4 * 8]);
      }
#pragma unroll
      for (int nf = 0; nf < 2; ++nf) {
        int n = wc * 32 + nf * 16 + (lane & 15);
        b1[nf] = *(const bf16x8*)(&sB1[p][n * 32 + s4 * 8]);
        b2[nf] = *(const bf16x8*)(&sB2[p][n * 32 + s4 * 8]);
      }
#pragma unroll
      for (int mf = 0; mf < 4; ++mf)
#pragma unroll
        for (int nf = 0; nf < 2; ++nf) {
          acc1[mf][nf] = __builtin_amdgcn_mfma_f32_16x16x32_bf16(a[mf], b1[nf], acc1[mf][nf], 0, 0, 0);
          acc2[mf][nf] = __builtin_amdgcn_mfma_f32_16x16x32_bf16(a[mf], b2[nf], acc2[mf][nf], 0, 0, 0);
        }
    }
    __builtin_amdgcn_s_setprio(0);
    __builtin_amdgcn_sched_barrier(0);
    __builtin_amdgcn_s_barrier();
    asm volatile("" ::: "memory");
    if (t + 2 < NT) stage(p, (t + 2) * 32);
  }

#pragma unroll
  for (int mf = 0; mf < 4; ++mf)
#pragma unroll
    for (int r = 0; r < 4; ++r) {
      int m = wr * 64 + mf * 16 + ((lane >> 4) << 2) + r;
      if (m0 + m < cnt) {
        size_t rowoff = (size_t)(bas + m0 + m) * HID + n0;
#pragma unroll
        for (int nf = 0; nf < 2; ++nf) {
          int col = wc * 32 + nf * 16 + (lane & 15);
          float d1 = acc1[mf][nf][r], d2 = acc2[mf][nf][r];
          h[rowoff + col] = (bf16_t)((d1 / (1.f + __expf(-d1))) * d2);
        }
      }
    }
}

// ---------------- GEMM2: eout[slot] = wt * (h @ W3) (proven R8 form, BK=64) ----------------
// tile 128m x 128n, 4 waves 2x2. grid = (DIM/128 = 8, MAXT). dbuf LDS 64 KB; vmcnt(8).
__global__ __launch_bounds__(256) void k_gemm2(
    const bf16_t* __restrict__ h, const bf16_t* __restrict__ w3t,
    const int* __restrict__ counts, const int* __restrict__ base,
    const int* __restrict__ tile_e, const int* __restrict__ tile_m0,
    const float* __restrict__ slot_wt, bf16_t* __restrict__ eout) {
  const int e = tile_e[blockIdx.y];
  if (e < 0) return;
  const int m0  = tile_m0[blockIdx.y];
  const int cnt = counts[e];
  const int bas = base[e];
  const int n0 = blockIdx.x * 128;
  const bf16_t* W = w3t + (size_t)e * (1024u * 2048u);

  __shared__ bf16_t sA[2][128 * 64];
  __shared__ bf16_t sB[2][128 * 64];

  const int tid = threadIdx.x, lane = tid & 63, wid = tid >> 6;
  const int wr = wid >> 1, wc = wid & 1;
  const int lr = lane >> 3, sw = (lane & 7) ^ lr;

  int rowA[4];
#pragma unroll
  for (int i = 0; i < 4; ++i) {
    int row = m0 + wid * 32 + i * 8 + lr;
    rowA[i] = bas + (row < cnt ? row : cnt - 1);
  }

  auto stage = [&](int p, int k0) {
#pragma unroll
    for (int i = 0; i < 4; ++i) {
      int rr = wid * 32 + i * 8;
      gload_lds16(h + (size_t)rowA[i] * HID + k0 + sw * 8, &sA[p][rr * 64]);
      gload_lds16(W + (size_t)(n0 + rr + lr) * 2048 + k0 + sw * 8, &sB[p][rr * 64]);
    }
  };

  f32x4 acc[4][4] = {};

  stage(0, 0);
  stage(1, 64);

  const int NT = HID / 64;  // 32
  for (int t = 0; t < NT; ++t) {
    const int p = t & 1;
    if (t + 2 < NT) asm volatile("s_waitcnt vmcnt(8)" ::: "memory");
    else            asm volatile("s_waitcnt vmcnt(0)" ::: "memory");
    __builtin_amdgcn_s_barrier();
    asm volatile("" ::: "memory");
    __builtin_amdgcn_s_setprio(1);
#pragma unroll
    for (int kk = 0; kk < 2; ++kk) {
      const int g = kk * 4 + (lane >> 4);
      bf16x8 a[4], b[4];
#pragma unroll
      for (int mf = 0; mf < 4; ++mf) {
        int r = wr * 64 + mf * 16 + (lane & 15);
        a[mf] = *(const bf16x8*)(&sA[p][r * 64 + ((g ^ (r & 7)) << 3)]);
      }
#pragma unroll
      for (int nf = 0; nf < 4; ++nf) {
        int n = wc * 64 + nf * 16 + (lane & 15);
        b[nf] = *(const bf16x8*)(&sB[p][n * 64 + ((g ^ (n & 7)) << 3)]);
      }
#pragma unroll
      for (int mf = 0; mf < 4; ++mf)
#pragma unroll
        for (int nf = 0; nf < 4; ++nf)
          acc[mf][nf] = __builtin_amdgcn_mfma_f32_16x16x32_bf16(a[mf], b[nf], acc[mf][nf], 0, 0, 0);
    }
    __builtin_amdgcn_s_setprio(0);
    __builtin_amdgcn_sched_barrier(0);
    __builtin_amdgcn_s_barrier();
    asm volatile("" ::: "memory");
    if (t + 2 < NT) stage(p, (t + 2) * 64);
  }

#pragma unroll
  for (int mf = 0; mf < 4; ++mf)
#pragma unroll
    for (int r = 0; r < 4; ++r) {
      int m = wr * 64 + mf * 16 + ((lane >> 4) << 2) + r;
      if (m0 + m < cnt) {
        int gs = bas + m0 + m;
        float wt = slot_wt[gs];
        size_t o = (size_t)gs * DIM + n0;
#pragma unroll
        for (int nf = 0; nf < 4; ++nf) {
          int col = wc * 64 + nf * 16 + (lane & 15);
          eout[o + col] = (bf16_t)(acc[mf][nf][r] * wt);
        }
      }
    }
}

// ---------------- combine: out[t] = eout[g0] + eout[g1] ----------------
__global__ __launch_bounds__(256) void k_combine(const bf16_t* __restrict__ eout,
    const int* __restrict__ slot_of, float* __restrict__ out) {
  const int t = blockIdx.x;
  const int c = threadIdx.x * 4;
  const int g0 = slot_of[2 * t], g1 = slot_of[2 * t + 1];
  bf16x4 a = *(const bf16x4*)(eout + (size_t)g0 * DIM + c);
  bf16x4 b = *(const bf16x4*)(eout + (size_t)g1 * DIM + c);
  float4 o;
  o.x = (float)a[0] + (float)b[0];
  o.y = (float)a[1] + (float)b[1];
  o.z = (float)a[2] + (float)b[2];
  o.w = (float)a[3] + (float)b[3];
  *(float4*)(out + (size_t)t * DIM + c) = o;
}

extern "C" void kernel_launch(void* const* d_in, const int* in_sizes, int n_in,
                              void* d_out, int out_size, void* d_ws, size_t ws_size,
                              hipStream_t stream) {
  const float* x   = (const float*)d_in[0];
  const float* rw  = (const float*)d_in[1];
  const float* rb  = (const float*)d_in[2];
  const float* w12 = (const float*)d_in[3];
  const float* w3  = (const float*)d_in[4];
  float* out = (float*)d_out;
  float* aux = out + (size_t)T_TOK * DIM;

  char* ws = (char*)d_ws;
  int*   counts     = (int*)(ws + 0);
  int*   fill       = (int*)(ws + 64);
  int*   base       = (int*)(ws + 128);
  int*   top_i      = (int*)(ws + 4096);
  float* top_w      = (float*)(ws + 4096 + 32768);
  int*   slot_token = (int*)(ws + 4096 + 65536);
  float* slot_wt    = (float*)(ws + 4096 + 98304);
  int*   slot_of    = (int*)(ws + 4096 + 131072);
  int*   tile_e     = (int*)(ws + 4096 + 163840);
  int*   tile_m0    = (int*)(ws + 4096 + 164352);
  bf16_t* xb        = (bf16_t*)(ws + 262144);                      // 8 MiB
  bf16_t* h         = (bf16_t*)(ws + 262144 + 8388608);            // 32 MiB
  bf16_t* wT        = (bf16_t*)(ws + 262144 + 8388608 + 33554432); // 64 MiB region:
                                                                   //   w12t (64M) during gemm1
                                                                   //   w3t (32M) + eout(16M) during gemm2
  bf16_t* eout      = (bf16_t*)((char*)wT + 33554432);
  // peak ws usage ≈ 104.3 MiB

  hipMemsetAsync(ws, 0, 256, stream);                 // counts/fill
  hipMemsetAsync(aux, 0, sizeof(float), stream);      // aux accumulator

  k_wt<<<dim3(64, 16, NE), dim3(256), 0, stream>>>(w12, wT, DIM, 2 * HID);
  k_router<<<dim3(T_TOK / 4), dim3(256), 0, stream>>>(x, rw, rb, counts, top_i, top_w,
                                                      aux, xb);
  k_plan<<<dim3(1), dim3(64), 0, stream>>>(counts, base, tile_e, tile_m0);
  k_gather<<<dim3(T_TOK / 256), dim3(256), 0, stream>>>(top_i, top_w, base, fill,
                                                        slot_token, slot_wt, slot_of);
  k_gemm1<<<dim3(HID / 64, MAXT), dim3(256), 0, stream>>>(
      xb, wT, counts, base, tile_e, tile_m0, slot_token, h);
  // w3t overwrites first half of w12t region (gemm1 done reading it)
  k_wt<<<dim3(16, 32, NE), dim3(256), 0, stream>>>(w3, wT, HID, DIM);
  k_gemm2<<<dim3(DIM / 128, MAXT), dim3(256), 0, stream>>>(
      h, wT, counts, base, tile_e, tile_m0, slot_wt, eout);
  k_combine<<<dim3(T_TOK), dim3(256), 0, stream>>>(eout, slot_of, out);
}

// Round 11
// 383.272 us; speedup vs baseline: 1.0781x; 1.0781x over previous
//
#include <hip/hip_runtime.h>
#include <hip/hip_bf16.h>
#include <stdint.h>

typedef __bf16 bf16_t;
typedef __bf16 bf16x8 __attribute__((ext_vector_type(8)));
typedef __bf16 bf16x4 __attribute__((ext_vector_type(4)));
typedef float f32x4 __attribute__((ext_vector_type(4)));

#define T_TOK 4096
#define DIM   1024
#define HID   2048
#define NE    8
#define MAXT  72   // max 128-row m-tiles: 8192/128 + 8

// async global->LDS, 16B per lane, LDS dest = wave-uniform base + lane*16
__device__ __forceinline__ void gload_lds16(const void* g, void* l) {
  __builtin_amdgcn_global_load_lds(
      (const __attribute__((address_space(1))) unsigned int*)g,
      (__attribute__((address_space(3))) unsigned int*)l, 16, 0, 0);
}

// ---------------- weight transpose+convert: in [K][N] f32 -> out [N][K] bf16 ----------------
// K-tile 128 x N-tile 64: output runs are 256B contiguous bf16 (vs 128B before).
__global__ __launch_bounds__(256) void k_wt(const float* __restrict__ in,
                                            bf16_t* __restrict__ out,
                                            int K, int N) {
  __shared__ float tile[128][65];   // 33.3 KB
  const size_t eoff = (size_t)blockIdx.z * K * N;
  const int k0 = blockIdx.y * 128, n0 = blockIdx.x * 64;
  const int tid = threadIdx.x;
#pragma unroll
  for (int it = 0; it < 8; ++it) {
    int k = (tid >> 4) + it * 16;
    int n = (tid & 15) * 4;
    float4 v = *(const float4*)(in + eoff + (size_t)(k0 + k) * N + n0 + n);
    tile[k][n] = v.x; tile[k][n + 1] = v.y; tile[k][n + 2] = v.z; tile[k][n + 3] = v.w;
  }
  __syncthreads();
#pragma unroll
  for (int it = 0; it < 4; ++it) {
    int n = (tid >> 4) + it * 16;
    int kc = (tid & 15) * 8;
    bf16x8 o;
#pragma unroll
    for (int j = 0; j < 8; ++j) o[j] = (bf16_t)tile[kc + j][n];
    *(bf16x8*)(out + eoff + (size_t)(n0 + n) * K + k0 + kc) = o;
  }
}

// ---------------- router (+ fused x->bf16): logits, sigmoid, top-2, aux ----------------
__global__ __launch_bounds__(256) void k_router(const float* __restrict__ x,
    const float* __restrict__ rw, const float* __restrict__ rb,
    int* __restrict__ counts, int* __restrict__ top_i, float* __restrict__ top_w,
    float* __restrict__ aux, bf16_t* __restrict__ xb) {
  int t = blockIdx.x * 4 + (threadIdx.x >> 6);
  int lane = threadIdx.x & 63;
  const float* xt = x + (size_t)t * DIM;
  float acc[8] = {0.f,0.f,0.f,0.f,0.f,0.f,0.f,0.f};
#pragma unroll
  for (int it = 0; it < 4; ++it) {
    int i = (it * 64 + lane) * 4;
    float4 xv = *(const float4*)(xt + i);
    bf16x4 o;
    o[0] = (bf16_t)xv.x; o[1] = (bf16_t)xv.y; o[2] = (bf16_t)xv.z; o[3] = (bf16_t)xv.w;
    *(bf16x4*)(xb + (size_t)t * DIM + i) = o;
#pragma unroll
    for (int c = 0; c < 4; ++c) {
      float v = (c == 0) ? xv.x : (c == 1) ? xv.y : (c == 2) ? xv.z : xv.w;
      float4 r0 = *(const float4*)(rw + (size_t)(i + c) * 8);
      float4 r1 = *(const float4*)(rw + (size_t)(i + c) * 8 + 4);
      acc[0] += v * r0.x; acc[1] += v * r0.y; acc[2] += v * r0.z; acc[3] += v * r0.w;
      acc[4] += v * r1.x; acc[5] += v * r1.y; acc[6] += v * r1.z; acc[7] += v * r1.w;
    }
  }
#pragma unroll
  for (int m = 32; m >= 1; m >>= 1) {
#pragma unroll
    for (int e = 0; e < 8; ++e) acc[e] += __shfl_xor(acc[e], m, 64);
  }
  if (lane == 0) {
    float s[8]; float sumsq = 0.f;
#pragma unroll
    for (int e = 0; e < 8; ++e) {
      float lg = acc[e] + rb[e];
      sumsq += lg * lg;
      s[e] = 1.f / (1.f + __expf(-lg));
    }
    int i1 = 0;
#pragma unroll
    for (int e = 1; e < 8; ++e) if (s[e] > s[i1]) i1 = e;
    int i2 = (i1 == 0) ? 1 : 0;
#pragma unroll
    for (int e = 0; e < 8; ++e) if (e != i1 && s[e] > s[i2]) i2 = e;
    float v1 = s[i1], v2 = s[i2];
    float den = v1 + v2 + 1e-6f;
    top_i[2 * t]     = i1; top_i[2 * t + 1] = i2;
    top_w[2 * t]     = v1 / den;
    top_w[2 * t + 1] = v2 / den;
    atomicAdd(&counts[i1], 1);
    atomicAdd(&counts[i2], 1);
    atomicAdd(aux, 0.01f * sumsq * (1.f / 32768.f));
  }
}

// ---------------- plan: base offsets + m-tile table ----------------
__global__ void k_plan(const int* __restrict__ counts, int* __restrict__ base,
                       int* __restrict__ tile_e, int* __restrict__ tile_m0) {
  if (threadIdx.x == 0) {
    int s = 0, nt = 0;
    for (int e = 0; e < NE; ++e) {
      base[e] = s;
      int c = counts[e];
      for (int m0 = 0; m0 < c; m0 += 128) { tile_e[nt] = e; tile_m0[nt] = m0; ++nt; }
      s += c;
    }
    for (; nt < MAXT; ++nt) tile_e[nt] = -1;
  }
}

// ---------------- gather tokens into per-expert slot lists ----------------
__global__ __launch_bounds__(256) void k_gather(const int* __restrict__ top_i,
    const float* __restrict__ top_w, const int* __restrict__ base,
    int* __restrict__ fill, int* __restrict__ slot_token, float* __restrict__ slot_wt,
    int* __restrict__ slot_of) {
  int t = blockIdx.x * 256 + threadIdx.x;
  if (t >= T_TOK) return;
#pragma unroll
  for (int j = 0; j < 2; ++j) {
    int e = top_i[2 * t + j];
    int p = atomicAdd(&fill[e], 1);
    int g = base[e] + p;
    slot_token[g] = t;
    slot_wt[g]    = top_w[2 * t + j];
    slot_of[2 * t + j] = g;
  }
}

// ---------------- GEMM1 + SwiGLU (proven R6/R8 optimum) ----------------
// tile 128m x 64n (two panels). 4 waves 2x2. grid = (HID/64 = 32, MAXT).
// dbuf LDS 64 KB; steady-state vmcnt(8), never 0 mid-loop. 16x16x32 MFMA, 0 conflicts.
__global__ __launch_bounds__(256) void k_gemm1(
    const bf16_t* __restrict__ xb, const bf16_t* __restrict__ w12t,
    const int* __restrict__ counts, const int* __restrict__ base,
    const int* __restrict__ tile_e, const int* __restrict__ tile_m0,
    const int* __restrict__ slot_token, bf16_t* __restrict__ h) {
  const int e = tile_e[blockIdx.y];
  if (e < 0) return;
  const int m0  = tile_m0[blockIdx.y];
  const int cnt = counts[e];
  const int bas = base[e];
  const int n0  = blockIdx.x * 64;          // hid col base, [0,2048)
  const bf16_t* W1 = w12t + (size_t)e * (4096u * 1024u) + (size_t)n0 * 1024u;
  const bf16_t* W2 = W1 + (size_t)2048 * 1024;

  __shared__ bf16_t sA[2][128 * 64];
  __shared__ bf16_t sB1[2][64 * 64];
  __shared__ bf16_t sB2[2][64 * 64];

  const int tid = threadIdx.x, lane = tid & 63, wid = tid >> 6;
  const int wr = wid >> 1, wc = wid & 1;
  const int lr = lane >> 3, sw = (lane & 7) ^ lr;  // swizzled source chunk

  int tokA[4];
#pragma unroll
  for (int i = 0; i < 4; ++i) {
    int row = m0 + wid * 32 + i * 8 + lr;
    tokA[i] = slot_token[bas + (row < cnt ? row : cnt - 1)];
  }

  auto stage = [&](int p, int k0) {
#pragma unroll
    for (int i = 0; i < 4; ++i)
      gload_lds16(xb + (size_t)tokA[i] * DIM + k0 + sw * 8,
                  &sA[p][(wid * 32 + i * 8) * 64]);
#pragma unroll
    for (int i = 0; i < 2; ++i) {
      int n = wid * 16 + i * 8 + lr;
      gload_lds16(W1 + (size_t)n * 1024 + k0 + sw * 8, &sB1[p][(wid * 16 + i * 8) * 64]);
      gload_lds16(W2 + (size_t)n * 1024 + k0 + sw * 8, &sB2[p][(wid * 16 + i * 8) * 64]);
    }
  };

  f32x4 acc1[4][2] = {};
  f32x4 acc2[4][2] = {};

  stage(0, 0);
  stage(1, 64);

  const int NT = DIM / 64;  // 16
  for (int t = 0; t < NT; ++t) {
    const int p = t & 1;
    if (t + 2 < NT) asm volatile("s_waitcnt vmcnt(8)" ::: "memory");
    else            asm volatile("s_waitcnt vmcnt(0)" ::: "memory");
    __builtin_amdgcn_s_barrier();
    asm volatile("" ::: "memory");
    __builtin_amdgcn_s_setprio(1);
#pragma unroll
    for (int kk = 0; kk < 2; ++kk) {
      const int g = kk * 4 + (lane >> 4);
      bf16x8 a[4], b1[2], b2[2];
#pragma unroll
      for (int mf = 0; mf < 4; ++mf) {
        int r = wr * 64 + mf * 16 + (lane & 15);
        a[mf] = *(const bf16x8*)(&sA[p][r * 64 + ((g ^ (r & 7)) << 3)]);
      }
#pragma unroll
      for (int nf = 0; nf < 2; ++nf) {
        int n = wc * 32 + nf * 16 + (lane & 15);
        b1[nf] = *(const bf16x8*)(&sB1[p][n * 64 + ((g ^ (n & 7)) << 3)]);
        b2[nf] = *(const bf16x8*)(&sB2[p][n * 64 + ((g ^ (n & 7)) << 3)]);
      }
#pragma unroll
      for (int mf = 0; mf < 4; ++mf)
#pragma unroll
        for (int nf = 0; nf < 2; ++nf) {
          acc1[mf][nf] = __builtin_amdgcn_mfma_f32_16x16x32_bf16(a[mf], b1[nf], acc1[mf][nf], 0, 0, 0);
          acc2[mf][nf] = __builtin_amdgcn_mfma_f32_16x16x32_bf16(a[mf], b2[nf], acc2[mf][nf], 0, 0, 0);
        }
    }
    __builtin_amdgcn_s_setprio(0);
    __builtin_amdgcn_sched_barrier(0);
    __builtin_amdgcn_s_barrier();
    asm volatile("" ::: "memory");
    if (t + 2 < NT) stage(p, (t + 2) * 64);
  }

#pragma unroll
  for (int mf = 0; mf < 4; ++mf)
#pragma unroll
    for (int r = 0; r < 4; ++r) {
      int m = wr * 64 + mf * 16 + ((lane >> 4) << 2) + r;
      if (m0 + m < cnt) {
        size_t rowoff = (size_t)(bas + m0 + m) * HID + n0;
#pragma unroll
        for (int nf = 0; nf < 2; ++nf) {
          int col = wc * 32 + nf * 16 + (lane & 15);
          float d1 = acc1[mf][nf][r], d2 = acc2[mf][nf][r];
          h[rowoff + col] = (bf16_t)((d1 / (1.f + __expf(-d1))) * d2);
        }
      }
    }
}

// ---------------- GEMM2: eout[slot] = wt * (h @ W3) (proven R8 form) ----------------
// tile 128m x 128n, 4 waves 2x2. grid = (DIM/128 = 8, MAXT). dbuf LDS 64 KB; vmcnt(8).
__global__ __launch_bounds__(256) void k_gemm2(
    const bf16_t* __restrict__ h, const bf16_t* __restrict__ w3t,
    const int* __restrict__ counts, const int* __restrict__ base,
    const int* __restrict__ tile_e, const int* __restrict__ tile_m0,
    const float* __restrict__ slot_wt, bf16_t* __restrict__ eout) {
  const int e = tile_e[blockIdx.y];
  if (e < 0) return;
  const int m0  = tile_m0[blockIdx.y];
  const int cnt = counts[e];
  const int bas = base[e];
  const int n0 = blockIdx.x * 128;
  const bf16_t* W = w3t + (size_t)e * (1024u * 2048u);

  __shared__ bf16_t sA[2][128 * 64];
  __shared__ bf16_t sB[2][128 * 64];

  const int tid = threadIdx.x, lane = tid & 63, wid = tid >> 6;
  const int wr = wid >> 1, wc = wid & 1;
  const int lr = lane >> 3, sw = (lane & 7) ^ lr;

  int rowA[4];
#pragma unroll
  for (int i = 0; i < 4; ++i) {
    int row = m0 + wid * 32 + i * 8 + lr;
    rowA[i] = bas + (row < cnt ? row : cnt - 1);
  }

  auto stage = [&](int p, int k0) {
#pragma unroll
    for (int i = 0; i < 4; ++i) {
      int rr = wid * 32 + i * 8;
      gload_lds16(h + (size_t)rowA[i] * HID + k0 + sw * 8, &sA[p][rr * 64]);
      gload_lds16(W + (size_t)(n0 + rr + lr) * 2048 + k0 + sw * 8, &sB[p][rr * 64]);
    }
  };

  f32x4 acc[4][4] = {};

  stage(0, 0);
  stage(1, 64);

  const int NT = HID / 64;  // 32
  for (int t = 0; t < NT; ++t) {
    const int p = t & 1;
    if (t + 2 < NT) asm volatile("s_waitcnt vmcnt(8)" ::: "memory");
    else            asm volatile("s_waitcnt vmcnt(0)" ::: "memory");
    __builtin_amdgcn_s_barrier();
    asm volatile("" ::: "memory");
    __builtin_amdgcn_s_setprio(1);
#pragma unroll
    for (int kk = 0; kk < 2; ++kk) {
      const int g = kk * 4 + (lane >> 4);
      bf16x8 a[4], b[4];
#pragma unroll
      for (int mf = 0; mf < 4; ++mf) {
        int r = wr * 64 + mf * 16 + (lane & 15);
        a[mf] = *(const bf16x8*)(&sA[p][r * 64 + ((g ^ (r & 7)) << 3)]);
      }
#pragma unroll
      for (int nf = 0; nf < 4; ++nf) {
        int n = wc * 64 + nf * 16 + (lane & 15);
        b[nf] = *(const bf16x8*)(&sB[p][n * 64 + ((g ^ (n & 7)) << 3)]);
      }
#pragma unroll
      for (int mf = 0; mf < 4; ++mf)
#pragma unroll
        for (int nf = 0; nf < 4; ++nf)
          acc[mf][nf] = __builtin_amdgcn_mfma_f32_16x16x32_bf16(a[mf], b[nf], acc[mf][nf], 0, 0, 0);
    }
    __builtin_amdgcn_s_setprio(0);
    __builtin_amdgcn_sched_barrier(0);
    __builtin_amdgcn_s_barrier();
    asm volatile("" ::: "memory");
    if (t + 2 < NT) stage(p, (t + 2) * 64);
  }

#pragma unroll
  for (int mf = 0; mf < 4; ++mf)
#pragma unroll
    for (int r = 0; r < 4; ++r) {
      int m = wr * 64 + mf * 16 + ((lane >> 4) << 2) + r;
      if (m0 + m < cnt) {
        int gs = bas + m0 + m;
        float wt = slot_wt[gs];
        size_t o = (size_t)gs * DIM + n0;
#pragma unroll
        for (int nf = 0; nf < 4; ++nf) {
          int col = wc * 64 + nf * 16 + (lane & 15);
          eout[o + col] = (bf16_t)(acc[mf][nf][r] * wt);
        }
      }
    }
}

// ---------------- combine: out[t] = eout[g0] + eout[g1] ----------------
__global__ __launch_bounds__(256) void k_combine(const bf16_t* __restrict__ eout,
    const int* __restrict__ slot_of, float* __restrict__ out) {
  const int t = blockIdx.x;
  const int c = threadIdx.x * 4;
  const int g0 = slot_of[2 * t], g1 = slot_of[2 * t + 1];
  bf16x4 a = *(const bf16x4*)(eout + (size_t)g0 * DIM + c);
  bf16x4 b = *(const bf16x4*)(eout + (size_t)g1 * DIM + c);
  float4 o;
  o.x = (float)a[0] + (float)b[0];
  o.y = (float)a[1] + (float)b[1];
  o.z = (float)a[2] + (float)b[2];
  o.w = (float)a[3] + (float)b[3];
  *(float4*)(out + (size_t)t * DIM + c) = o;
}

extern "C" void kernel_launch(void* const* d_in, const int* in_sizes, int n_in,
                              void* d_out, int out_size, void* d_ws, size_t ws_size,
                              hipStream_t stream) {
  const float* x   = (const float*)d_in[0];
  const float* rw  = (const float*)d_in[1];
  const float* rb  = (const float*)d_in[2];
  const float* w12 = (const float*)d_in[3];
  const float* w3  = (const float*)d_in[4];
  float* out = (float*)d_out;
  float* aux = out + (size_t)T_TOK * DIM;

  char* ws = (char*)d_ws;
  int*   counts     = (int*)(ws + 0);
  int*   fill       = (int*)(ws + 64);
  int*   base       = (int*)(ws + 128);
  int*   top_i      = (int*)(ws + 4096);
  float* top_w      = (float*)(ws + 4096 + 32768);
  int*   slot_token = (int*)(ws + 4096 + 65536);
  float* slot_wt    = (float*)(ws + 4096 + 98304);
  int*   slot_of    = (int*)(ws + 4096 + 131072);
  int*   tile_e     = (int*)(ws + 4096 + 163840);
  int*   tile_m0    = (int*)(ws + 4096 + 164352);
  bf16_t* xb        = (bf16_t*)(ws + 262144);                      // 8 MiB
  bf16_t* h         = (bf16_t*)(ws + 262144 + 8388608);            // 32 MiB
  bf16_t* wT        = (bf16_t*)(ws + 262144 + 8388608 + 33554432); // 64 MiB region:
                                                                   //   w12t (64M) during gemm1
                                                                   //   w3t (32M) + eout(16M) during gemm2
  bf16_t* eout      = (bf16_t*)((char*)wT + 33554432);
  // peak ws usage ≈ 104.3 MiB

  hipMemsetAsync(ws, 0, 256, stream);                 // counts/fill
  hipMemsetAsync(aux, 0, sizeof(float), stream);      // aux accumulator

  k_wt<<<dim3(64, 8, NE), dim3(256), 0, stream>>>(w12, wT, DIM, 2 * HID);
  k_router<<<dim3(T_TOK / 4), dim3(256), 0, stream>>>(x, rw, rb, counts, top_i, top_w,
                                                      aux, xb);
  k_plan<<<dim3(1), dim3(64), 0, stream>>>(counts, base, tile_e, tile_m0);
  k_gather<<<dim3(T_TOK / 256), dim3(256), 0, stream>>>(top_i, top_w, base, fill,
                                                        slot_token, slot_wt, slot_of);
  k_gemm1<<<dim3(HID / 64, MAXT), dim3(256), 0, stream>>>(
      xb, wT, counts, base, tile_e, tile_m0, slot_token, h);
  // w3t overwrites first half of w12t region (gemm1 done reading it)
  k_wt<<<dim3(16, 16, NE), dim3(256), 0, stream>>>(w3, wT, HID, DIM);
  k_gemm2<<<dim3(DIM / 128, MAXT), dim3(256), 0, stream>>>(
      h, wT, counts, base, tile_e, tile_m0, slot_wt, eout);
  k_combine<<<dim3(T_TOK), dim3(256), 0, stream>>>(eout, slot_of, out);
}

// Round 12
// 366.252 us; speedup vs baseline: 1.1282x; 1.0465x over previous
//
#include <hip/hip_runtime.h>
#include <hip/hip_bf16.h>
#include <stdint.h>

typedef __bf16 bf16_t;
typedef __bf16 bf16x8 __attribute__((ext_vector_type(8)));
typedef __bf16 bf16x4 __attribute__((ext_vector_type(4)));
typedef float f32x4 __attribute__((ext_vector_type(4)));

#define T_TOK 4096
#define DIM   1024
#define HID   2048
#define NE    8
#define MAXT  72   // max 128-row m-tiles: 8192/128 + 8

// async global->LDS, 16B per lane, LDS dest = wave-uniform base + lane*16
__device__ __forceinline__ void gload_lds16(const void* g, void* l) {
  __builtin_amdgcn_global_load_lds(
      (const __attribute__((address_space(1))) unsigned int*)g,
      (__attribute__((address_space(3))) unsigned int*)l, 16, 0, 0);
}

// ---------------- merged pre-pass: w12^T, w3^T, router(+x->bf16) in ONE launch ----------------
// blocks [0,4096): w12 [1024][4096] f32 -> w12t [e][4096][1024] bf16
// blocks [4096,6144): w3 [2048][1024] f32 -> w3t [e][1024][2048] bf16
// blocks [6144,7168): router + x->bf16
__device__ __forceinline__ void wt_tile(const float* __restrict__ in,
                                        bf16_t* __restrict__ out,
                                        int K, int N, int e, int ky, int nx,
                                        float (*tile)[65]) {
  const size_t eoff = (size_t)e * K * N;
  const int k0 = ky * 128, n0 = nx * 64;
  const int tid = threadIdx.x;
#pragma unroll
  for (int it = 0; it < 8; ++it) {
    int k = (tid >> 4) + it * 16;
    int n = (tid & 15) * 4;
    float4 v = *(const float4*)(in + eoff + (size_t)(k0 + k) * N + n0 + n);
    tile[k][n] = v.x; tile[k][n + 1] = v.y; tile[k][n + 2] = v.z; tile[k][n + 3] = v.w;
  }
  __syncthreads();
#pragma unroll
  for (int it = 0; it < 4; ++it) {
    int n = (tid >> 4) + it * 16;
    int kc = (tid & 15) * 8;
    bf16x8 o;
#pragma unroll
    for (int j = 0; j < 8; ++j) o[j] = (bf16_t)tile[kc + j][n];
    *(bf16x8*)(out + eoff + (size_t)(n0 + n) * K + k0 + kc) = o;
  }
}

__global__ __launch_bounds__(256) void k_prep(
    const float* __restrict__ x, const float* __restrict__ rw,
    const float* __restrict__ rb, const float* __restrict__ w12,
    const float* __restrict__ w3, bf16_t* __restrict__ xb,
    bf16_t* __restrict__ w12t, bf16_t* __restrict__ w3t,
    int* __restrict__ counts, int* __restrict__ top_i, float* __restrict__ top_w,
    float* __restrict__ aux) {
  __shared__ float tile[128][65];   // 33.3 KB (transpose branches only)
  const int b = blockIdx.x;
  if (b < 4096) {               // w12^T: K=1024 (8 k-tiles), N=4096 (64 n-tiles)
    int e = b >> 9, rem = b & 511;
    wt_tile(w12, w12t, DIM, 2 * HID, e, rem >> 6, rem & 63, tile);
    return;
  }
  if (b < 6144) {               // w3^T: K=2048 (16 k-tiles), N=1024 (16 n-tiles)
    int lb = b - 4096;
    int e = lb >> 8, rem = lb & 255;
    wt_tile(w3, w3t, HID, DIM, e, rem >> 4, rem & 15, tile);
    return;
  }
  // ---- router + x->bf16 ----
  int t = (b - 6144) * 4 + (threadIdx.x >> 6);
  int lane = threadIdx.x & 63;
  const float* xt = x + (size_t)t * DIM;
  float acc[8] = {0.f,0.f,0.f,0.f,0.f,0.f,0.f,0.f};
#pragma unroll
  for (int it = 0; it < 4; ++it) {
    int i = (it * 64 + lane) * 4;
    float4 xv = *(const float4*)(xt + i);
    bf16x4 o;
    o[0] = (bf16_t)xv.x; o[1] = (bf16_t)xv.y; o[2] = (bf16_t)xv.z; o[3] = (bf16_t)xv.w;
    *(bf16x4*)(xb + (size_t)t * DIM + i) = o;
#pragma unroll
    for (int c = 0; c < 4; ++c) {
      float v = (c == 0) ? xv.x : (c == 1) ? xv.y : (c == 2) ? xv.z : xv.w;
      float4 r0 = *(const float4*)(rw + (size_t)(i + c) * 8);
      float4 r1 = *(const float4*)(rw + (size_t)(i + c) * 8 + 4);
      acc[0] += v * r0.x; acc[1] += v * r0.y; acc[2] += v * r0.z; acc[3] += v * r0.w;
      acc[4] += v * r1.x; acc[5] += v * r1.y; acc[6] += v * r1.z; acc[7] += v * r1.w;
    }
  }
#pragma unroll
  for (int m = 32; m >= 1; m >>= 1) {
#pragma unroll
    for (int e = 0; e < 8; ++e) acc[e] += __shfl_xor(acc[e], m, 64);
  }
  if (lane == 0) {
    float s[8]; float sumsq = 0.f;
#pragma unroll
    for (int e = 0; e < 8; ++e) {
      float lg = acc[e] + rb[e];
      sumsq += lg * lg;
      s[e] = 1.f / (1.f + __expf(-lg));
    }
    int i1 = 0;
#pragma unroll
    for (int e = 1; e < 8; ++e) if (s[e] > s[i1]) i1 = e;
    int i2 = (i1 == 0) ? 1 : 0;
#pragma unroll
    for (int e = 0; e < 8; ++e) if (e != i1 && s[e] > s[i2]) i2 = e;
    float v1 = s[i1], v2 = s[i2];
    float den = v1 + v2 + 1e-6f;
    top_i[2 * t]     = i1; top_i[2 * t + 1] = i2;
    top_w[2 * t]     = v1 / den;
    top_w[2 * t + 1] = v2 / den;
    atomicAdd(&counts[i1], 1);
    atomicAdd(&counts[i2], 1);
    atomicAdd(aux, 0.01f * sumsq * (1.f / 32768.f));
  }
}

// ---------------- plan: base offsets + m-tile table ----------------
__global__ void k_plan(const int* __restrict__ counts, int* __restrict__ base,
                       int* __restrict__ tile_e, int* __restrict__ tile_m0) {
  if (threadIdx.x == 0) {
    int s = 0, nt = 0;
    for (int e = 0; e < NE; ++e) {
      base[e] = s;
      int c = counts[e];
      for (int m0 = 0; m0 < c; m0 += 128) { tile_e[nt] = e; tile_m0[nt] = m0; ++nt; }
      s += c;
    }
    for (; nt < MAXT; ++nt) tile_e[nt] = -1;
  }
}

// ---------------- gather tokens into per-expert slot lists ----------------
__global__ __launch_bounds__(256) void k_gather(const int* __restrict__ top_i,
    const float* __restrict__ top_w, const int* __restrict__ base,
    int* __restrict__ fill, int* __restrict__ slot_token, float* __restrict__ slot_wt,
    int* __restrict__ slot_of) {
  int t = blockIdx.x * 256 + threadIdx.x;
  if (t >= T_TOK) return;
#pragma unroll
  for (int j = 0; j < 2; ++j) {
    int e = top_i[2 * t + j];
    int p = atomicAdd(&fill[e], 1);
    int g = base[e] + p;
    slot_token[g] = t;
    slot_wt[g]    = top_w[2 * t + j];
    slot_of[2 * t + j] = g;
  }
}

// ---------------- GEMM1 + SwiGLU (proven R6/R8 optimum, unchanged) ----------------
__global__ __launch_bounds__(256) void k_gemm1(
    const bf16_t* __restrict__ xb, const bf16_t* __restrict__ w12t,
    const int* __restrict__ counts, const int* __restrict__ base,
    const int* __restrict__ tile_e, const int* __restrict__ tile_m0,
    const int* __restrict__ slot_token, bf16_t* __restrict__ h) {
  const int e = tile_e[blockIdx.y];
  if (e < 0) return;
  const int m0  = tile_m0[blockIdx.y];
  const int cnt = counts[e];
  const int bas = base[e];
  const int n0  = blockIdx.x * 64;          // hid col base, [0,2048)
  const bf16_t* W1 = w12t + (size_t)e * (4096u * 1024u) + (size_t)n0 * 1024u;
  const bf16_t* W2 = W1 + (size_t)2048 * 1024;

  __shared__ bf16_t sA[2][128 * 64];
  __shared__ bf16_t sB1[2][64 * 64];
  __shared__ bf16_t sB2[2][64 * 64];

  const int tid = threadIdx.x, lane = tid & 63, wid = tid >> 6;
  const int wr = wid >> 1, wc = wid & 1;
  const int lr = lane >> 3, sw = (lane & 7) ^ lr;  // swizzled source chunk

  int tokA[4];
#pragma unroll
  for (int i = 0; i < 4; ++i) {
    int row = m0 + wid * 32 + i * 8 + lr;
    tokA[i] = slot_token[bas + (row < cnt ? row : cnt - 1)];
  }

  auto stage = [&](int p, int k0) {
#pragma unroll
    for (int i = 0; i < 4; ++i)
      gload_lds16(xb + (size_t)tokA[i] * DIM + k0 + sw * 8,
                  &sA[p][(wid * 32 + i * 8) * 64]);
#pragma unroll
    for (int i = 0; i < 2; ++i) {
      int n = wid * 16 + i * 8 + lr;
      gload_lds16(W1 + (size_t)n * 1024 + k0 + sw * 8, &sB1[p][(wid * 16 + i * 8) * 64]);
      gload_lds16(W2 + (size_t)n * 1024 + k0 + sw * 8, &sB2[p][(wid * 16 + i * 8) * 64]);
    }
  };

  f32x4 acc1[4][2] = {};
  f32x4 acc2[4][2] = {};

  stage(0, 0);
  stage(1, 64);

  const int NT = DIM / 64;  // 16
  for (int t = 0; t < NT; ++t) {
    const int p = t & 1;
    if (t + 2 < NT) asm volatile("s_waitcnt vmcnt(8)" ::: "memory");
    else            asm volatile("s_waitcnt vmcnt(0)" ::: "memory");
    __builtin_amdgcn_s_barrier();
    asm volatile("" ::: "memory");
    __builtin_amdgcn_s_setprio(1);
#pragma unroll
    for (int kk = 0; kk < 2; ++kk) {
      const int g = kk * 4 + (lane >> 4);
      bf16x8 a[4], b1[2], b2[2];
#pragma unroll
      for (int mf = 0; mf < 4; ++mf) {
        int r = wr * 64 + mf * 16 + (lane & 15);
        a[mf] = *(const bf16x8*)(&sA[p][r * 64 + ((g ^ (r & 7)) << 3)]);
      }
#pragma unroll
      for (int nf = 0; nf < 2; ++nf) {
        int n = wc * 32 + nf * 16 + (lane & 15);
        b1[nf] = *(const bf16x8*)(&sB1[p][n * 64 + ((g ^ (n & 7)) << 3)]);
        b2[nf] = *(const bf16x8*)(&sB2[p][n * 64 + ((g ^ (n & 7)) << 3)]);
      }
#pragma unroll
      for (int mf = 0; mf < 4; ++mf)
#pragma unroll
        for (int nf = 0; nf < 2; ++nf) {
          acc1[mf][nf] = __builtin_amdgcn_mfma_f32_16x16x32_bf16(a[mf], b1[nf], acc1[mf][nf], 0, 0, 0);
          acc2[mf][nf] = __builtin_amdgcn_mfma_f32_16x16x32_bf16(a[mf], b2[nf], acc2[mf][nf], 0, 0, 0);
        }
    }
    __builtin_amdgcn_s_setprio(0);
    __builtin_amdgcn_sched_barrier(0);
    __builtin_amdgcn_s_barrier();
    asm volatile("" ::: "memory");
    if (t + 2 < NT) stage(p, (t + 2) * 64);
  }

#pragma unroll
  for (int mf = 0; mf < 4; ++mf)
#pragma unroll
    for (int r = 0; r < 4; ++r) {
      int m = wr * 64 + mf * 16 + ((lane >> 4) << 2) + r;
      if (m0 + m < cnt) {
        size_t rowoff = (size_t)(bas + m0 + m) * HID + n0;
#pragma unroll
        for (int nf = 0; nf < 2; ++nf) {
          int col = wc * 32 + nf * 16 + (lane & 15);
          float d1 = acc1[mf][nf][r], d2 = acc2[mf][nf][r];
          h[rowoff + col] = (bf16_t)((d1 / (1.f + __expf(-d1))) * d2);
        }
      }
    }
}

// ---------------- GEMM2: eout[slot] = wt * (h @ W3) (proven R8 form, unchanged) ----------------
__global__ __launch_bounds__(256) void k_gemm2(
    const bf16_t* __restrict__ h, const bf16_t* __restrict__ w3t,
    const int* __restrict__ counts, const int* __restrict__ base,
    const int* __restrict__ tile_e, const int* __restrict__ tile_m0,
    const float* __restrict__ slot_wt, bf16_t* __restrict__ eout) {
  const int e = tile_e[blockIdx.y];
  if (e < 0) return;
  const int m0  = tile_m0[blockIdx.y];
  const int cnt = counts[e];
  const int bas = base[e];
  const int n0 = blockIdx.x * 128;
  const bf16_t* W = w3t + (size_t)e * (1024u * 2048u);

  __shared__ bf16_t sA[2][128 * 64];
  __shared__ bf16_t sB[2][128 * 64];

  const int tid = threadIdx.x, lane = tid & 63, wid = tid >> 6;
  const int wr = wid >> 1, wc = wid & 1;
  const int lr = lane >> 3, sw = (lane & 7) ^ lr;

  int rowA[4];
#pragma unroll
  for (int i = 0; i < 4; ++i) {
    int row = m0 + wid * 32 + i * 8 + lr;
    rowA[i] = bas + (row < cnt ? row : cnt - 1);
  }

  auto stage = [&](int p, int k0) {
#pragma unroll
    for (int i = 0; i < 4; ++i) {
      int rr = wid * 32 + i * 8;
      gload_lds16(h + (size_t)rowA[i] * HID + k0 + sw * 8, &sA[p][rr * 64]);
      gload_lds16(W + (size_t)(n0 + rr + lr) * 2048 + k0 + sw * 8, &sB[p][rr * 64]);
    }
  };

  f32x4 acc[4][4] = {};

  stage(0, 0);
  stage(1, 64);

  const int NT = HID / 64;  // 32
  for (int t = 0; t < NT; ++t) {
    const int p = t & 1;
    if (t + 2 < NT) asm volatile("s_waitcnt vmcnt(8)" ::: "memory");
    else            asm volatile("s_waitcnt vmcnt(0)" ::: "memory");
    __builtin_amdgcn_s_barrier();
    asm volatile("" ::: "memory");
    __builtin_amdgcn_s_setprio(1);
#pragma unroll
    for (int kk = 0; kk < 2; ++kk) {
      const int g = kk * 4 + (lane >> 4);
      bf16x8 a[4], b[4];
#pragma unroll
      for (int mf = 0; mf < 4; ++mf) {
        int r = wr * 64 + mf * 16 + (lane & 15);
        a[mf] = *(const bf16x8*)(&sA[p][r * 64 + ((g ^ (r & 7)) << 3)]);
      }
#pragma unroll
      for (int nf = 0; nf < 4; ++nf) {
        int n = wc * 64 + nf * 16 + (lane & 15);
        b[nf] = *(const bf16x8*)(&sB[p][n * 64 + ((g ^ (n & 7)) << 3)]);
      }
#pragma unroll
      for (int mf = 0; mf < 4; ++mf)
#pragma unroll
        for (int nf = 0; nf < 4; ++nf)
          acc[mf][nf] = __builtin_amdgcn_mfma_f32_16x16x32_bf16(a[mf], b[nf], acc[mf][nf], 0, 0, 0);
    }
    __builtin_amdgcn_s_setprio(0);
    __builtin_amdgcn_sched_barrier(0);
    __builtin_amdgcn_s_barrier();
    asm volatile("" ::: "memory");
    if (t + 2 < NT) stage(p, (t + 2) * 64);
  }

#pragma unroll
  for (int mf = 0; mf < 4; ++mf)
#pragma unroll
    for (int r = 0; r < 4; ++r) {
      int m = wr * 64 + mf * 16 + ((lane >> 4) << 2) + r;
      if (m0 + m < cnt) {
        int gs = bas + m0 + m;
        float wt = slot_wt[gs];
        size_t o = (size_t)gs * DIM + n0;
#pragma unroll
        for (int nf = 0; nf < 4; ++nf) {
          int col = wc * 64 + nf * 16 + (lane & 15);
          eout[o + col] = (bf16_t)(acc[mf][nf][r] * wt);
        }
      }
    }
}

// ---------------- combine: out[t] = eout[g0] + eout[g1] ----------------
__global__ __launch_bounds__(256) void k_combine(const bf16_t* __restrict__ eout,
    const int* __restrict__ slot_of, float* __restrict__ out) {
  const int t = blockIdx.x;
  const int c = threadIdx.x * 4;
  const int g0 = slot_of[2 * t], g1 = slot_of[2 * t + 1];
  bf16x4 a = *(const bf16x4*)(eout + (size_t)g0 * DIM + c);
  bf16x4 b = *(const bf16x4*)(eout + (size_t)g1 * DIM + c);
  float4 o;
  o.x = (float)a[0] + (float)b[0];
  o.y = (float)a[1] + (float)b[1];
  o.z = (float)a[2] + (float)b[2];
  o.w = (float)a[3] + (float)b[3];
  *(float4*)(out + (size_t)t * DIM + c) = o;
}

extern "C" void kernel_launch(void* const* d_in, const int* in_sizes, int n_in,
                              void* d_out, int out_size, void* d_ws, size_t ws_size,
                              hipStream_t stream) {
  const float* x   = (const float*)d_in[0];
  const float* rw  = (const float*)d_in[1];
  const float* rb  = (const float*)d_in[2];
  const float* w12 = (const float*)d_in[3];
  const float* w3  = (const float*)d_in[4];
  float* out = (float*)d_out;
  float* aux = out + (size_t)T_TOK * DIM;

  char* ws = (char*)d_ws;
  int*   counts     = (int*)(ws + 0);
  int*   fill       = (int*)(ws + 64);
  int*   base       = (int*)(ws + 128);
  int*   top_i      = (int*)(ws + 4096);
  float* top_w      = (float*)(ws + 4096 + 32768);
  int*   slot_token = (int*)(ws + 4096 + 65536);
  float* slot_wt    = (float*)(ws + 4096 + 98304);
  int*   slot_of    = (int*)(ws + 4096 + 131072);
  int*   tile_e     = (int*)(ws + 4096 + 163840);
  int*   tile_m0    = (int*)(ws + 4096 + 164352);
  bf16_t* xb        = (bf16_t*)(ws + 262144);                       // 8 MiB
  bf16_t* h         = (bf16_t*)(ws + 262144 + 8388608);             // 32 MiB
  bf16_t* w12t      = (bf16_t*)(ws + 262144 + 8388608 + 33554432);  // 64 MiB
  bf16_t* w3t       = (bf16_t*)((char*)w12t + 67108864);            // 32 MiB
  bf16_t* eout      = w12t;  // aliases w12t region during gemm2 (w12t dead by then)
  // peak ws usage = 142,868,480 B — identical to R2's proven-safe footprint

  hipMemsetAsync(ws, 0, 256, stream);                 // counts/fill
  hipMemsetAsync(aux, 0, sizeof(float), stream);      // aux accumulator

  // merged independent pre-work: w12^T (4096 blocks) + w3^T (2048) + router (1024)
  k_prep<<<dim3(7168), dim3(256), 0, stream>>>(x, rw, rb, w12, w3, xb, w12t, w3t,
                                               counts, top_i, top_w, aux);
  k_plan<<<dim3(1), dim3(64), 0, stream>>>(counts, base, tile_e, tile_m0);
  k_gather<<<dim3(T_TOK / 256), dim3(256), 0, stream>>>(top_i, top_w, base, fill,
                                                        slot_token, slot_wt, slot_of);
  k_gemm1<<<dim3(HID / 64, MAXT), dim3(256), 0, stream>>>(
      xb, w12t, counts, base, tile_e, tile_m0, slot_token, h);
  k_gemm2<<<dim3(DIM / 128, MAXT), dim3(256), 0, stream>>>(
      h, w3t, counts, base, tile_e, tile_m0, slot_wt, eout);
  k_combine<<<dim3(T_TOK), dim3(256), 0, stream>>>(eout, slot_of, out);
}